// Round 1
// 1010.524 us; speedup vs baseline: 1.0784x; 1.0784x over previous
//
#include <hip/hip_runtime.h>
#include <stdint.h>

#define M_DIM 16384
#define N_DIM 4096
#define K_DIM 4096

#define BM 256
#define BN 256
#define BK 64
#define NT (K_DIM / BK)   // 64 K-tiles

typedef __attribute__((ext_vector_type(8))) short short8;   // 8 bf16 (4 VGPRs)
typedef __attribute__((ext_vector_type(4))) float f32x4;    // 4 fp32 acc

__device__ __forceinline__ unsigned short f32_bf16(float f) {
    union { float f; unsigned int u; } v; v.f = f;
    unsigned int u = v.u;
    unsigned int r = u + 0x7FFFu + ((u >> 16) & 1u);   // RNE
    return (unsigned short)(r >> 16);
}

// fp32 -> bf16, 8 elems/thread, exact grid (n % 2048 == 0)
__global__ __launch_bounds__(256) void cvt_f32_to_bf16(
        const float* __restrict__ src, unsigned short* __restrict__ dst) {
    size_t i = ((size_t)blockIdx.x * 256 + threadIdx.x) * 8;
    const float4* s = (const float4*)(src + i);
    float4 a = s[0];
    float4 b = s[1];
    uint4 o;
    o.x = (unsigned)f32_bf16(a.x) | ((unsigned)f32_bf16(a.y) << 16);
    o.y = (unsigned)f32_bf16(a.z) | ((unsigned)f32_bf16(a.w) << 16);
    o.z = (unsigned)f32_bf16(b.x) | ((unsigned)f32_bf16(b.y) << 16);
    o.w = (unsigned)f32_bf16(b.z) | ((unsigned)f32_bf16(b.w) << 16);
    *(uint4*)(dst + i) = o;
}

// ---------------------------------------------------------------------------
// C[M,N] = A[M,K] * B[N,K]^T + bias ; A,B bf16, C fp32.
// 256x256 8-phase template (m201 structure): BK=64, 8 waves (2M x 4N),
// 128 KiB double-buffered LDS, global_load_lds width=16 with pre-swizzled
// global source (XOR chunk ^= row&7) + swizzled ds_read, counted vmcnt(4)
// once per K-tile, setprio around MFMA clusters, XCD-bijective block swizzle.
// ---------------------------------------------------------------------------

#define GLDS(gp, sp)                                                          \
    __builtin_amdgcn_global_load_lds(                                         \
        (const __attribute__((address_space(1))) void*)(gp),                  \
        (__attribute__((address_space(3))) void*)(sp), 16, 0, 0)

// one half-tile = 128 rows x 64 cols bf16 = 2 global_load_lds (512 thr x 16 B)
#define STAGE_HALF_A(b, R0, kt) do {                                          \
    GLDS(gA + (size_t)(R0) * K_DIM + (kt) * BK,                               \
         &sA[b][((R0) + wave * 8) * BK]);                                     \
    GLDS(gA + (size_t)((R0) + 64) * K_DIM + (kt) * BK,                        \
         &sA[b][((R0) + 64 + wave * 8) * BK]);                                \
} while (0)
#define STAGE_HALF_B(b, R0, kt) do {                                          \
    GLDS(gB + (size_t)(R0) * K_DIM + (kt) * BK,                               \
         &sB[b][((R0) + wave * 8) * BK]);                                     \
    GLDS(gB + (size_t)((R0) + 64) * K_DIM + (kt) * BK,                        \
         &sB[b][((R0) + 64 + wave * 8) * BK]);                                \
} while (0)

// register subtile loads (swizzled ds_read): r&7 == lane&7 for all frag rows
#define LDA(mh) do {                                                          \
    _Pragma("unroll")                                                         \
    for (int i4 = 0; i4 < 4; ++i4) {                                          \
        af[i4][0] = *(const short8*)(pA + oA0 + ((mh) * 64 + i4 * 16) * BK);  \
        af[i4][1] = *(const short8*)(pA + oA1 + ((mh) * 64 + i4 * 16) * BK);  \
    }                                                                         \
} while (0)
#define LDB(jh) do {                                                          \
    _Pragma("unroll")                                                         \
    for (int j2 = 0; j2 < 2; ++j2) {                                          \
        bf[j2][0] = *(const short8*)(pB + oB0 + ((jh) * 32 + j2 * 16) * BK);  \
        bf[j2][1] = *(const short8*)(pB + oB1 + ((jh) * 32 + j2 * 16) * BK);  \
    }                                                                         \
} while (0)

// 16 MFMA = one C-quadrant (4 M-frags x 2 N-frags) x K=64.
// ks outermost: each acc reg's two updates are 8 MFMAs apart (no RAW stall).
#define MM(mh, jh) do {                                                       \
    __builtin_amdgcn_s_setprio(1);                                            \
    _Pragma("unroll")                                                         \
    for (int ks = 0; ks < 2; ++ks)                                            \
    _Pragma("unroll")                                                         \
    for (int i4 = 0; i4 < 4; ++i4)                                            \
    _Pragma("unroll")                                                         \
    for (int j2 = 0; j2 < 2; ++j2)                                            \
        acc[(mh) * 4 + i4][(jh) * 2 + j2] =                                   \
            __builtin_amdgcn_mfma_f32_16x16x32_bf16(                          \
                af[i4][ks], bf[j2][ks],                                       \
                acc[(mh) * 4 + i4][(jh) * 2 + j2], 0, 0, 0);                  \
    __builtin_amdgcn_s_setprio(0);                                            \
} while (0)

#define BAR()        __builtin_amdgcn_s_barrier()
#define WAIT_LGKM0() asm volatile("s_waitcnt lgkmcnt(0)" ::: "memory")

__global__ __launch_bounds__(512, 2) void gemm256_bias(
        const unsigned short* __restrict__ A,
        const unsigned short* __restrict__ B,
        const float* __restrict__ bias,
        float* __restrict__ C) {
    __shared__ __align__(16) unsigned short sA[2][BM * BK];   // 2 x 32 KiB
    __shared__ __align__(16) unsigned short sB[2][BN * BK];   // 2 x 32 KiB

    const int tid  = threadIdx.x;
    const int wave = tid >> 6;        // 0..7
    const int lane = tid & 63;
    const int wm   = wave >> 2;       // 0..1 (M half of tile)
    const int wn   = wave & 3;        // 0..3 (N quarter of tile)
    const int quad = lane >> 4;
    const int m16  = lane & 15;

    // XCD-bijective swizzle; grid = 1024 (%8==0). bm-fast within an XCD chunk:
    // 2 B-panels (4 MiB) stay L2-resident per XCD; A streams via L3.
    const int cpx = gridDim.x >> 3;
    const int swz = ((int)blockIdx.x & 7) * cpx + ((int)blockIdx.x >> 3);
    const int bm  = swz & 63;          // M_DIM/BM == 64
    const int bn  = swz >> 6;          // N_DIM/BN == 16

    // staging source: lane covers row wave*8+(lane>>3) (+R0, +c*64),
    // col chunk pre-swizzled so linear LDS write lands at swizzled position
    const int ldr  = lane >> 3;                    // row&7 of staged row
    const int swzc = ((lane & 7) ^ ldr) << 3;      // inverse-swizzled col (elems)
    const unsigned short* gA = A + (size_t)(bm * BM + wave * 8 + ldr) * K_DIM + swzc;
    const unsigned short* gB = B + (size_t)(bn * BN + wave * 8 + ldr) * K_DIM + swzc;

    // ds_read base offsets (elems); frag rows are m16 + 16k so row&7 == lane&7
    const int sl0 = quad ^ (lane & 7);             // k-slice 0 chunk
    const int sl1 = (quad + 4) ^ (lane & 7);       // k-slice 1 chunk
    const int oA0 = (wm * 128 + m16) * BK + sl0 * 8;
    const int oA1 = (wm * 128 + m16) * BK + sl1 * 8;
    const int oB0 = (wn * 64 + m16) * BK + sl0 * 8;
    const int oB1 = (wn * 64 + m16) * BK + sl1 * 8;

    f32x4 acc[8][4] = {};
    short8 af[4][2], bf[2][2];

    // prologue: K-tile 0 fully (8 loads) + A of K-tile 1 (4 loads) -> vmcnt(4)
    STAGE_HALF_A(0, 0, 0); STAGE_HALF_A(0, 128, 0);
    STAGE_HALF_B(0, 0, 0); STAGE_HALF_B(0, 128, 0);
    STAGE_HALF_A(1, 0, 1); STAGE_HALF_A(1, 128, 1);
    asm volatile("s_waitcnt vmcnt(4)" ::: "memory");
    BAR();

#pragma unroll 2
    for (int kt = 0; kt < NT; ++kt) {
        const int buf = kt & 1;
        const unsigned short* pA = sA[buf];
        const unsigned short* pB = sB[buf];

        // ---- phase 1: quadrant (M0,N0); prefetch B(kt+1) into buf^1 ----
        // (buf^1's B regions dead since (kt-1)'s phase-4 barrier)
        LDA(0); LDB(0);                            // 12 ds_reads
        if (kt + 1 < NT) { STAGE_HALF_B(buf ^ 1, 0, kt + 1);
                           STAGE_HALF_B(buf ^ 1, 128, kt + 1); }
        asm volatile("s_waitcnt lgkmcnt(8)" ::: "memory");
        BAR(); WAIT_LGKM0();
        MM(0, 0);
        BAR();

        // ---- phase 2: (M0,N1) ----
        LDB(1);                                    // 4 ds_reads
        BAR(); WAIT_LGKM0();
        MM(0, 1);
        BAR();

        // ---- phase 3: (M1,N1) ----
        LDA(1);                                    // 8 ds_reads (last A reads)
        BAR(); WAIT_LGKM0();
        MM(1, 1);
        BAR();

        // ---- phase 4: (M1,N0); prefetch A(kt+2) into THIS buf ----
        // (kt's A regions dead: all waves passed phase-3 lgkmcnt(0)+barrier)
        LDB(0);                                    // 4 ds_reads (re-read N0)
        if (kt + 2 < NT) { STAGE_HALF_A(buf, 0, kt + 2);
                           STAGE_HALF_A(buf, 128, kt + 2); }
        BAR(); WAIT_LGKM0();
        MM(1, 0);
        // counted drain: only the 4 A(kt+2) loads may stay in flight
        if (kt + 2 < NT) asm volatile("s_waitcnt vmcnt(4)" ::: "memory");
        else             asm volatile("s_waitcnt vmcnt(0)" ::: "memory");
        BAR();
    }

    // epilogue: C/D layout col=lane&15, row=quad*4+reg ; bias fused
    const int col0 = bn * BN + wn * 64 + m16;
    float bv[4];
#pragma unroll
    for (int j = 0; j < 4; ++j) bv[j] = bias[col0 + j * 16];

#pragma unroll
    for (int i = 0; i < 8; ++i) {
#pragma unroll
        for (int r = 0; r < 4; ++r) {
            const int m = bm * BM + wm * 128 + i * 16 + quad * 4 + r;
            float* crow = C + (size_t)m * N_DIM + col0;
#pragma unroll
            for (int j = 0; j < 4; ++j) crow[j * 16] = acc[i][j][r] + bv[j];
        }
    }
}

extern "C" void kernel_launch(void* const* d_in, const int* in_sizes, int n_in,
                              void* d_out, int out_size, void* d_ws, size_t ws_size,
                              hipStream_t stream) {
    const float* x    = (const float*)d_in[0];   // [8,2048,4096] = [16384,4096]
    const float* w    = (const float*)d_in[1];   // [4096,4096]
    const float* bias = (const float*)d_in[2];   // [4096]
    float* out        = (float*)d_out;           // [16384,4096]

    // workspace: xb (128 MiB) + wb (32 MiB) = 160 MiB of d_ws
    unsigned short* xb = (unsigned short*)d_ws;
    unsigned short* wb = xb + (size_t)M_DIM * K_DIM;

    cvt_f32_to_bf16<<<(M_DIM * (size_t)K_DIM) / 2048, 256, 0, stream>>>(x, xb);
    cvt_f32_to_bf16<<<(N_DIM * (size_t)K_DIM) / 2048, 256, 0, stream>>>(w, wb);

    gemm256_bias<<<dim3((M_DIM / BM) * (N_DIM / BN)), 512, 0, stream>>>(
        xb, wb, bias, out);
}

// Round 2
// 980.641 us; speedup vs baseline: 1.1112x; 1.0305x over previous
//
#include <hip/hip_runtime.h>
#include <stdint.h>

#define M_DIM 16384
#define N_DIM 4096
#define K_DIM 4096

#define BM 256
#define BN 256
#define BK 64
#define NT (K_DIM / BK)     // 64 K-tiles
#define NITER (NT / 2)      // 32 iterations x 2 K-tiles

typedef __attribute__((ext_vector_type(8))) short short8;   // 8 bf16 (4 VGPRs)
typedef __attribute__((ext_vector_type(4))) float f32x4;    // 4 fp32 acc

__device__ __forceinline__ unsigned short f32_bf16(float f) {
    union { float f; unsigned int u; } v; v.f = f;
    unsigned int u = v.u;
    unsigned int r = u + 0x7FFFu + ((u >> 16) & 1u);   // RNE
    return (unsigned short)(r >> 16);
}

// fp32 -> bf16, grid-stride (2048 blocks), 8 elems/thread/iter
__global__ __launch_bounds__(256) void cvt_f32_to_bf16(
        const float* __restrict__ src, unsigned short* __restrict__ dst,
        size_t n8) {
    const size_t stride = (size_t)gridDim.x * 256;
    for (size_t i = (size_t)blockIdx.x * 256 + threadIdx.x; i < n8; i += stride) {
        const size_t e = i * 8;
        const float4* s = (const float4*)(src + e);
        float4 a = s[0];
        float4 b = s[1];
        uint4 o;
        o.x = (unsigned)f32_bf16(a.x) | ((unsigned)f32_bf16(a.y) << 16);
        o.y = (unsigned)f32_bf16(a.z) | ((unsigned)f32_bf16(a.w) << 16);
        o.z = (unsigned)f32_bf16(b.x) | ((unsigned)f32_bf16(b.y) << 16);
        o.w = (unsigned)f32_bf16(b.z) | ((unsigned)f32_bf16(b.w) << 16);
        *(uint4*)(dst + e) = o;
    }
}

// ---------------------------------------------------------------------------
// C[M,N] = A[M,K] * B[N,K]^T + bias ; A,B bf16, C fp32.
// Faithful m201 8-phase template: 256x256 tile, BK=64, 8 waves (2M x 4N),
// 128 KiB double-buffered LDS, ONE half-tile (2 global_load_lds w=16) staged
// PER PHASE, counted vmcnt(2) only at phases 4/8, XOR-swizzled LDS
// (pre-swizzled global source + swizzled ds_read), setprio around MFMA,
// XCD-bijective block swizzle, bias fused in epilogue.
// ---------------------------------------------------------------------------

#define GLDS(gp, sp)                                                          \
    __builtin_amdgcn_global_load_lds(                                         \
        (const __attribute__((address_space(1))) void*)(gp),                  \
        (__attribute__((address_space(3))) void*)(sp), 16, 0, 0)

// half-tile stage: 128 rows x 64 cols bf16 = 2 gloads (512 thr x 16 B each).
// gA/gB already carry (tile_row + wave*8 + ldr)*K_DIM + swzc.
#define STAGE_AL(b, kt) do {                                                  \
    GLDS(gA + (size_t)(kt) * BK,                  &sA[b][        wave * 512]);\
    GLDS(gA + (size_t)64 * K_DIM + (kt) * BK,     &sA[b][64*BK + wave * 512]);\
} while (0)
#define STAGE_AH(b, kt) do {                                                  \
    GLDS(gA + (size_t)128 * K_DIM + (kt) * BK,    &sA[b][128*BK + wave * 512]);\
    GLDS(gA + (size_t)192 * K_DIM + (kt) * BK,    &sA[b][192*BK + wave * 512]);\
} while (0)
#define STAGE_BL(b, kt) do {                                                  \
    GLDS(gB + (size_t)(kt) * BK,                  &sB[b][        wave * 512]);\
    GLDS(gB + (size_t)64 * K_DIM + (kt) * BK,     &sB[b][64*BK + wave * 512]);\
} while (0)
#define STAGE_BH(b, kt) do {                                                  \
    GLDS(gB + (size_t)128 * K_DIM + (kt) * BK,    &sB[b][128*BK + wave * 512]);\
    GLDS(gB + (size_t)192 * K_DIM + (kt) * BK,    &sB[b][192*BK + wave * 512]);\
} while (0)

// register fragment loads (swizzled ds_read_b128)
#define LDA(pT, mh) do {                                                      \
    _Pragma("unroll")                                                         \
    for (int i4 = 0; i4 < 4; ++i4) {                                          \
        af[i4][0] = *(const short8*)((pT) + oA0 + ((mh) * 64 + i4 * 16) * BK);\
        af[i4][1] = *(const short8*)((pT) + oA1 + ((mh) * 64 + i4 * 16) * BK);\
    }                                                                         \
} while (0)
#define LDB0(pT) do {                                                         \
    _Pragma("unroll")                                                         \
    for (int j2 = 0; j2 < 2; ++j2) {                                          \
        bf0[j2][0] = *(const short8*)((pT) + oB0 + (j2 * 16) * BK);           \
        bf0[j2][1] = *(const short8*)((pT) + oB1 + (j2 * 16) * BK);           \
    }                                                                         \
} while (0)
#define LDB1(pT) do {                                                         \
    _Pragma("unroll")                                                         \
    for (int j2 = 0; j2 < 2; ++j2) {                                          \
        bf1[j2][0] = *(const short8*)((pT) + oB0 + (32 + j2 * 16) * BK);      \
        bf1[j2][1] = *(const short8*)((pT) + oB1 + (32 + j2 * 16) * BK);      \
    }                                                                         \
} while (0)

// 16 MFMA = one C-quadrant (4 M-frags x 2 N-frags) x K=64.
// ks outermost: each acc reg's two updates are 8 MFMAs apart.
#define MM(mh, jh, bfx) do {                                                  \
    __builtin_amdgcn_s_setprio(1);                                            \
    _Pragma("unroll")                                                         \
    for (int ks = 0; ks < 2; ++ks)                                            \
    _Pragma("unroll")                                                         \
    for (int i4 = 0; i4 < 4; ++i4)                                            \
    _Pragma("unroll")                                                         \
    for (int j2 = 0; j2 < 2; ++j2)                                            \
        acc[(mh) * 4 + i4][(jh) * 2 + j2] =                                   \
            __builtin_amdgcn_mfma_f32_16x16x32_bf16(                          \
                af[i4][ks], bfx[j2][ks],                                      \
                acc[(mh) * 4 + i4][(jh) * 2 + j2], 0, 0, 0);                  \
    __builtin_amdgcn_s_setprio(0);                                            \
} while (0)

#define BAR()        __builtin_amdgcn_s_barrier()
#define WAIT_LGKM0() asm volatile("s_waitcnt lgkmcnt(0)" ::: "memory")
#define WAIT_LGKM8() asm volatile("s_waitcnt lgkmcnt(8)" ::: "memory")
#define WAIT_VM(n)   asm volatile("s_waitcnt vmcnt(" #n ")" ::: "memory")

__global__ __launch_bounds__(512, 2) void gemm256_bias(
        const unsigned short* __restrict__ A,
        const unsigned short* __restrict__ B,
        const float* __restrict__ bias,
        float* __restrict__ C) {
    __shared__ __align__(16) unsigned short sA[2][BM * BK];   // 2 x 32 KiB
    __shared__ __align__(16) unsigned short sB[2][BN * BK];   // 2 x 32 KiB

    const int tid  = threadIdx.x;
    const int wave = tid >> 6;        // 0..7
    const int lane = tid & 63;
    const int wm   = wave >> 2;       // 0..1 (M half)
    const int wn   = wave & 3;        // 0..3 (N quarter)
    const int quad = lane >> 4;
    const int m16  = lane & 15;

    // XCD-bijective swizzle; grid = 1024 (%8==0), bm-fast within XCD chunk
    const int cpx = gridDim.x >> 3;
    const int swz = ((int)blockIdx.x & 7) * cpx + ((int)blockIdx.x >> 3);
    const int bm  = swz & 63;          // M_DIM/BM == 64
    const int bn  = swz >> 6;          // N_DIM/BN == 16

    // staging source: lane covers row wave*8+ldr, col chunk pre-swizzled so the
    // linear global_load_lds write lands at the swizzled position
    const int ldr  = lane >> 3;                    // row&7 of staged row
    const int swzc = ((lane & 7) ^ ldr) << 3;      // inverse-swizzled col chunk
    const unsigned short* gA = A + (size_t)(bm * BM + wave * 8 + ldr) * K_DIM + swzc;
    const unsigned short* gB = B + (size_t)(bn * BN + wave * 8 + ldr) * K_DIM + swzc;

    // ds_read offsets (elems); fragment rows are m16+16k so row&7 == lane&7
    const int sl0 = quad ^ (lane & 7);             // k-slice 0 chunk (k 0..31)
    const int sl1 = (quad + 4) ^ (lane & 7);       // k-slice 1 chunk (k 32..63)
    const int oA0 = (wm * 128 + m16) * BK + sl0 * 8;
    const int oA1 = (wm * 128 + m16) * BK + sl1 * 8;
    const int oB0 = (wn * 64 + m16) * BK + sl0 * 8;
    const int oB1 = (wn * 64 + m16) * BK + sl1 * 8;

    f32x4 acc[8][4] = {};
    short8 af[4][2], bf0[2][2], bf1[2][2];

    // prologue: K-tile 0 fully (4 half-tiles) + A-lo of K-tile 1 (P8' slot)
    STAGE_AL(0, 0); STAGE_AH(0, 0); STAGE_BL(0, 0); STAGE_BH(0, 0);
    STAGE_AL(1, 1);
    WAIT_VM(2);
    BAR();

#pragma unroll 1
    for (int it = 0; it < NITER; ++it) {
        const int t0 = 2 * it, t1 = t0 + 1;
        const bool more = (it + 1 < NITER);

        // ================= K-tile t0 (buf 0) =================
        // P1: (M0,N0) | stage A-hi(t1)
        LDA(sA[0], 0); LDB0(sB[0]);                // 12 ds_reads
        STAGE_AH(1, t1);
        WAIT_LGKM8();
        BAR(); WAIT_LGKM0();
        MM(0, 0, bf0);
        BAR();

        // P2: (M0,N1) | stage B-lo(t1)
        LDB1(sB[0]);                               // 4 ds_reads
        STAGE_BL(1, t1);
        BAR(); WAIT_LGKM0();
        MM(0, 1, bf1);
        BAR();

        // P3: (M1,N1) | stage B-hi(t1)
        LDA(sA[0], 1);                             // 8 ds_reads
        STAGE_BH(1, t1);
        BAR(); WAIT_LGKM0();
        MM(1, 1, bf1);
        BAR();

        // P4: (M1,N0) pure MFMA | stage A-lo(t0+2) | counted drain
        if (more) STAGE_AL(0, t0 + 2);
        BAR();
        MM(1, 0, bf0);
        if (more) WAIT_VM(2); else WAIT_VM(0);     // t1's 4 half-tiles landed
        BAR();

        // ================= K-tile t1 (buf 1) =================
        // P5: (M0,N0) | stage A-hi(t0+2)
        LDA(sA[1], 0); LDB0(sB[1]);                // 12 ds_reads
        if (more) STAGE_AH(0, t0 + 2);
        WAIT_LGKM8();
        BAR(); WAIT_LGKM0();
        MM(0, 0, bf0);
        BAR();

        // P6: (M0,N1) | stage B-lo(t0+2)
        LDB1(sB[1]);                               // 4 ds_reads
        if (more) STAGE_BL(0, t0 + 2);
        BAR(); WAIT_LGKM0();
        MM(0, 1, bf1);
        BAR();

        // P7: (M1,N1) | stage B-hi(t0+2)
        LDA(sA[1], 1);                             // 8 ds_reads
        if (more) STAGE_BH(0, t0 + 2);
        BAR(); WAIT_LGKM0();
        MM(1, 1, bf1);
        BAR();

        // P8: (M1,N0) pure MFMA | stage A-lo(t1+2) | counted drain
        if (more) STAGE_AL(1, t1 + 2);
        BAR();
        MM(1, 0, bf0);
        if (more) WAIT_VM(2); else WAIT_VM(0);     // t0+2's 4 half-tiles landed
        BAR();
    }

    // epilogue: C/D layout col=lane&15, row=quad*4+reg ; bias fused
    const int col0 = bn * BN + wn * 64 + m16;
    float bv[4];
#pragma unroll
    for (int j = 0; j < 4; ++j) bv[j] = bias[col0 + j * 16];

#pragma unroll
    for (int i = 0; i < 8; ++i) {
#pragma unroll
        for (int r = 0; r < 4; ++r) {
            const int m = bm * BM + wm * 128 + i * 16 + quad * 4 + r;
            float* crow = C + (size_t)m * N_DIM + col0;
#pragma unroll
            for (int j = 0; j < 4; ++j) crow[j * 16] = acc[i][j][r] + bv[j];
        }
    }
}

extern "C" void kernel_launch(void* const* d_in, const int* in_sizes, int n_in,
                              void* d_out, int out_size, void* d_ws, size_t ws_size,
                              hipStream_t stream) {
    const float* x    = (const float*)d_in[0];   // [8,2048,4096] = [16384,4096]
    const float* w    = (const float*)d_in[1];   // [4096,4096]
    const float* bias = (const float*)d_in[2];   // [4096]
    float* out        = (float*)d_out;           // [16384,4096]

    // workspace: xb (128 MiB) + wb (32 MiB) of d_ws
    unsigned short* xb = (unsigned short*)d_ws;
    unsigned short* wb = xb + (size_t)M_DIM * K_DIM;

    cvt_f32_to_bf16<<<2048, 256, 0, stream>>>(x, xb, ((size_t)M_DIM * K_DIM) / 8);
    cvt_f32_to_bf16<<<2048, 256, 0, stream>>>(w, wb, ((size_t)N_DIM * K_DIM) / 8);

    gemm256_bias<<<dim3((M_DIM / BM) * (N_DIM / BN)), 512, 0, stream>>>(
        xb, wb, bias, out);
}